// Round 20
// baseline (235.086 us; speedup 1.0000x reference)
//
#include <hip/hip_runtime.h>
#include <hip/hip_bf16.h>

#define NUM_HEADS 4
#define HD 256
#define QD 256
#define VD 256
#define B_SZ 32
#define N_NODES 8192
#define NEG_SLOPE 0.2f
#define CH 16            // rows per chunk
#define NCH 32           // chunks per 512-row strip
#define KSTRIDE 1040     // key LDS row stride bytes

typedef short bf16x8 __attribute__((ext_vector_type(8)));
typedef float f32x4 __attribute__((ext_vector_type(4)));

static __device__ __forceinline__ unsigned short f2bf(float f) {
    __hip_bfloat16 h = __float2bfloat16(f);
    return *reinterpret_cast<unsigned short*>(&h);
}

static __device__ __forceinline__ void gload_lds16(const float* g, void* l) {
    __builtin_amdgcn_global_load_lds(
        (const __attribute__((address_space(1))) void*)g,
        (__attribute__((address_space(3))) void*)l, 16, 0, 0);
}

// ---------------------------------------------------------------------------
// Kernel 1: prep  (hqb + swizzled WqP pack; unchanged)
// ---------------------------------------------------------------------------
__global__ __launch_bounds__(256)
void prep_kernel(const float* __restrict__ query,
                 const float* __restrict__ Wq,
                 const float* __restrict__ bq,
                 unsigned short* __restrict__ WqP,
                 float* __restrict__ hqb) {
    int blk = blockIdx.x;
    int tid = threadIdx.x;
    if (blk < 32) {
        int b = blk, col = tid;
        float acc = 2.0f * bq[col];
#pragma unroll 16
        for (int k = 0; k < QD; ++k)
            acc += query[b * QD + k] * Wq[k * HD + col];
        hqb[b * HD + col] = acc;
    } else {
        int idx = blk - 32;
        int kstep = idx >> 2, g = idx & 3;
        int col = tid;
        int h = col >> 6, ct = (col >> 4) & 3, col16 = col & 15;
        unsigned short v[8];
#pragma unroll
        for (int j = 0; j < 8; ++j)
            v[j] = f2bf(Wq[(kstep * 32 + g * 8 + j) * HD + col]);
        *reinterpret_cast<uint4*>(
            WqP + kstep * 8192 + h * 2048 + ct * 512 + (g * 16 + col16) * 8) =
            *reinterpret_cast<uint4*>(v);
    }
}

// ---------------------------------------------------------------------------
// Kernel 2 (FUSED, ct-split): grid 512 = (b, 512-row strip), 512 thr, 8 waves,
// CH=16, LDS 66.5 KB -> 2 blocks/CU = 4 waves/SIMD (2x latency hiding).
// Wave w = (head h=w&3, ct-half cth=w>>2):
//   bfr[8][2] = 64 VGPR -> TRULY persistent (no per-chunk L2 reload).
//   16 MFMA/chunk, dot-partial over 32 d, partner exchange via 512B LDS,
//   masked online softmax over own 8 rows, PV over own 8 rows.
// ---------------------------------------------------------------------------
__global__ __launch_bounds__(512, 4)
void fused_kernel(const float* __restrict__ key,
                  const float* __restrict__ value,
                  const unsigned short* __restrict__ WqP,
                  const float* __restrict__ hqb,
                  const float* __restrict__ avec,
                  float* __restrict__ s,
                  float* __restrict__ p_part,
                  float* __restrict__ pml) {
    __shared__ __align__(16) char smem[2 * (CH * KSTRIDE) + 2 * (CH * 1024) + 512];
    char* kb0 = smem;
    char* kb1 = smem + CH * KSTRIDE;
    char* vb0 = smem + 2 * CH * KSTRIDE;
    char* vb1 = vb0 + CH * 1024;
    float (*xbuf)[2][16] = reinterpret_cast<float(*)[2][16]>(vb1 + CH * 1024); // [h][cth][row]

    int bid = blockIdx.x;
    int b = bid >> 4, strip = bid & 15;
    int tid = threadIdx.x;
    int w = tid >> 6, lane = tid & 63;
    int col16 = lane & 15, g = (lane >> 4) & 3;
    int h = w & 3, cth = w >> 2;
    int rowbase0 = strip * 512;

    // ---- persistent B-fragments: my head, my ct-half: 16 x bf16x8 = 64 VGPR
    bf16x8 bfr[8][2];
    {
        const unsigned short* wp0 = WqP + h * 2048 + cth * 1024 + (g * 16 + col16) * 8;
#pragma unroll
        for (int ks = 0; ks < 8; ++ks)
#pragma unroll
            for (int ctl = 0; ctl < 2; ++ctl)
                bfr[ks][ctl] = *reinterpret_cast<const bf16x8*>(wp0 + ks * 8192 + ctl * 512);
    }
    // per-lane d-constants: d = (cth*2+ctl)*16 + g*4 + r
    float av8[2][4], hq8[2][4];
#pragma unroll
    for (int ctl = 0; ctl < 2; ++ctl)
#pragma unroll
        for (int r = 0; r < 4; ++r) {
            int d = (cth * 2 + ctl) * 16 + g * 4 + r;
            av8[ctl][r] = avec[d];
            hq8[ctl][r] = hqb[b * HD + h * 64 + d];
        }

    float mr = -1e30f, lr = 0.f;
    f32x4 pa = (f32x4){0.f, 0.f, 0.f, 0.f};

    // ---- prologue: wave w stages key rows 2w,2w+1 and value rows 2w,2w+1
    {
        int rb = rowbase0;
#pragma unroll
        for (int r = 0; r < 2; ++r) {
            int lr_ = w * 2 + r;
            gload_lds16(key + ((size_t)(b * N_NODES + rb + lr_)) * QD + lane * 4,
                        kb0 + lr_ * KSTRIDE);
            gload_lds16(value + ((size_t)(b * N_NODES + rb + lr_)) * VD + lane * 4,
                        vb0 + lr_ * 1024);
        }
    }

    for (int t = 0; t < NCH; ++t) {
        __builtin_amdgcn_s_barrier();          // all done computing t-1
        if (t + 1 < NCH) {
            char* kbn = ((t + 1) & 1) ? kb1 : kb0;
            char* vbn = ((t + 1) & 1) ? vb1 : vb0;
            int rb = rowbase0 + (t + 1) * CH;
#pragma unroll
            for (int r = 0; r < 2; ++r) {
                int lr_ = w * 2 + r;
                gload_lds16(key + ((size_t)(b * N_NODES + rb + lr_)) * QD + lane * 4,
                            kbn + lr_ * KSTRIDE);
            }
#pragma unroll
            for (int r = 0; r < 2; ++r) {
                int lr_ = w * 2 + r;
                gload_lds16(value + ((size_t)(b * N_NODES + rb + lr_)) * VD + lane * 4,
                            vbn + lr_ * 1024);
            }
            // outstanding: loads(t)[4] (+store t-1) + loads(t+1)[4] -> vmcnt(4)
            asm volatile("s_waitcnt vmcnt(4)" ::: "memory");
        } else {
            asm volatile("s_waitcnt vmcnt(0)" ::: "memory");
        }
        __builtin_amdgcn_s_barrier();          // everyone's chunk-t loads landed
        __builtin_amdgcn_sched_barrier(0);

        const char* kb = (t & 1) ? kb1 : kb0;
        const char* vb = (t & 1) ? vb1 : vb0;
        int n0c = rowbase0 + t * CH;

        // ---- MFMA in two ks-halves (a[4] live at a time, keeps VGPR <=128)
        f32x4 acc[2];
        acc[0] = (f32x4){0.f, 0.f, 0.f, 0.f};
        acc[1] = acc[0];
#pragma unroll
        for (int kh = 0; kh < 2; ++kh) {
            bf16x8 a[4];
#pragma unroll
            for (int k2 = 0; k2 < 4; ++k2) {
                int ks = kh * 4 + k2;
                f32x4 lo = *reinterpret_cast<const f32x4*>(kb + col16 * KSTRIDE + ks * 128 + g * 32);
                f32x4 hi = *reinterpret_cast<const f32x4*>(kb + col16 * KSTRIDE + ks * 128 + g * 32 + 16);
                unsigned int u0, u1, u2, u3;
                asm("v_cvt_pk_bf16_f32 %0, %1, %2" : "=v"(u0) : "v"(lo[0]), "v"(lo[1]));
                asm("v_cvt_pk_bf16_f32 %0, %1, %2" : "=v"(u1) : "v"(lo[2]), "v"(lo[3]));
                asm("v_cvt_pk_bf16_f32 %0, %1, %2" : "=v"(u2) : "v"(hi[0]), "v"(hi[1]));
                asm("v_cvt_pk_bf16_f32 %0, %1, %2" : "=v"(u3) : "v"(hi[2]), "v"(hi[3]));
                uint4 tt = {u0, u1, u2, u3};
                a[k2] = *reinterpret_cast<bf16x8*>(&tt);
            }
#pragma unroll
            for (int k2 = 0; k2 < 4; ++k2)
#pragma unroll
                for (int ctl = 0; ctl < 2; ++ctl)
                    acc[ctl] = __builtin_amdgcn_mfma_f32_16x16x32_bf16(
                        bfr[kh * 4 + k2][ctl], a[k2], acc[ctl], 0, 0, 0);
        }

        // ---- dot-partial over my 32 d-values (8 FMA + 2 shfl)
        float dp = 0.f;
#pragma unroll
        for (int ctl = 0; ctl < 2; ++ctl)
#pragma unroll
            for (int r = 0; r < 4; ++r) {
                float pre = acc[ctl][r] + hq8[ctl][r];
                float tv = fmaxf(pre, NEG_SLOPE * pre);
                dp += av8[ctl][r] * tv;
            }
        dp += __shfl_xor(dp, 16, 64);
        dp += __shfl_xor(dp, 32, 64);   // dup over g; partial over my 32 d

        // ---- exchange with partner ct-half
        if (lane < 16) xbuf[h][cth][col16] = dp;
        __syncthreads();                // xbuf visible (also drains t+1 loads:
                                        // they've had the MFMA phase to land)
        float pfull = dp + xbuf[h][1 - cth][col16];

        if (cth == 0 && lane < 16)
            s[((size_t)(b * NUM_HEADS + h)) * N_NODES + n0c + lane] = pfull;

        // ---- masked online softmax over my 8 rows (col16>>3 == cth)
        float mydot = ((col16 >> 3) == cth) ? pfull : -1e30f;
        float mc = mydot;
        mc = fmaxf(mc, __shfl_xor(mc, 1, 64));
        mc = fmaxf(mc, __shfl_xor(mc, 2, 64));
        mc = fmaxf(mc, __shfl_xor(mc, 4, 64));
        mc = fmaxf(mc, __shfl_xor(mc, 8, 64));
        float mnew = fmaxf(mr, mc);
        float ep = __expf(mydot - mnew);        // 0 for other-half lanes
        float lc = ep;
        lc += __shfl_xor(lc, 1, 64);
        lc += __shfl_xor(lc, 2, 64);
        lc += __shfl_xor(lc, 4, 64);
        lc += __shfl_xor(lc, 8, 64);
        float scf = __expf(mr - mnew);
        pa *= scf;
        lr = lr * scf + lc;
        mr = mnew;

        // ---- PV over my 8 rows
#pragma unroll
        for (int n = 0; n < 8; ++n) {
            int row = cth * 8 + n;
            f32x4 v = *reinterpret_cast<const f32x4*>(vb + row * 1024 + lane * 16);
            float e = __shfl(ep, row, 64);
            pa += e * v;
        }
    }

    // ---- per-wave output slot: (b*16+strip)*8 + cth*4 + h
    int slot = bid * 8 + cth * 4 + h;
    *reinterpret_cast<f32x4*>(p_part + (size_t)slot * 256 + lane * 4) = pa;
    if (lane == 0) {
        pml[slot * 2] = mr;
        pml[slot * 2 + 1] = lr;
    }
}

// ---------------------------------------------------------------------------
// Kernel 3: final. Per (b,h): 32 slots (16 strips x 2 ct-halves), two-pass
// (no register arrays); global M,L; rescale-reduce; @Wv + bias + relu.
// ---------------------------------------------------------------------------
__global__ __launch_bounds__(256)
void final_kernel(const float* __restrict__ p_part,
                  const float* __restrict__ pml,
                  const float* __restrict__ Wv,
                  const float* __restrict__ bv,
                  float* __restrict__ hout,
                  float* __restrict__ sc) {
    int bh = blockIdx.x;
    int b = bh >> 2, h = bh & 3;
    int tid = threadIdx.x;

    float M = -1e30f;
#pragma unroll 8
    for (int i = 0; i < 32; ++i) {
        int slot = (b * 16 + (i >> 1)) * 8 + (i & 1) * 4 + h;
        M = fmaxf(M, pml[slot * 2]);
    }
    float L = 0.f, acc = 0.f;
#pragma unroll 8
    for (int i = 0; i < 32; ++i) {
        int slot = (b * 16 + (i >> 1)) * 8 + (i & 1) * 4 + h;
        float wf = __expf(pml[slot * 2] - M);
        L += wf * pml[slot * 2 + 1];
        acc += wf * p_part[(size_t)slot * 256 + tid];
    }
    float invL = 1.0f / L;
    if (tid == 0) {
        sc[bh * 2] = M;
        sc[bh * 2 + 1] = invL;
    }
    __shared__ float ps[256];
    ps[tid] = acc * invL;
    __syncthreads();

    int d = tid & 63, kr = tid >> 6;
    float a2 = 0.f;
#pragma unroll 8
    for (int k = kr * 64; k < kr * 64 + 64; ++k)
        a2 += ps[k] * Wv[k * HD + h * 64 + d];
    __shared__ float rs[4][64];
    rs[kr][d] = a2;
    __syncthreads();
    if (tid < 64) {
        float o = bv[h * 64 + tid] + rs[0][tid] + rs[1][tid] + rs[2][tid] + rs[3][tid];
        hout[b * HD + h * 64 + tid] = fmaxf(o, 0.f);
    }
}

// ---------------------------------------------------------------------------
// Kernel 4: e-pass. e_out[b,n,h] = exp(s[b,h,n]-M)*invL.
// ---------------------------------------------------------------------------
__global__ __launch_bounds__(256)
void epass_kernel(const float* __restrict__ s,
                  const float* __restrict__ sc,
                  float* __restrict__ e_out) {
    int bid = blockIdx.x;
    int b = bid >> 5, t = bid & 31;
    int n = t * 256 + threadIdx.x;
    float4 ev;
#pragma unroll
    for (int h = 0; h < 4; ++h) {
        float M = sc[(b * 4 + h) * 2];
        float invL = sc[(b * 4 + h) * 2 + 1];
        float sv = s[((size_t)(b * 4 + h)) * N_NODES + n];
        (&ev.x)[h] = __expf(sv - M) * invL;
    }
    *reinterpret_cast<float4*>(e_out + ((size_t)(b * N_NODES + n)) * 4) = ev;
}

extern "C" void kernel_launch(void* const* d_in, const int* in_sizes, int n_in,
                              void* d_out, int out_size, void* d_ws, size_t ws_size,
                              hipStream_t stream) {
    const float* query = (const float*)d_in[0];
    const float* key   = (const float*)d_in[1];
    const float* value = (const float*)d_in[2];
    const float* Wq    = (const float*)d_in[3];
    const float* bq    = (const float*)d_in[4];
    const float* Wv    = (const float*)d_in[5];
    const float* bv    = (const float*)d_in[6];
    const float* avec  = (const float*)d_in[7];
    float* out = (float*)d_out;

    char* ws = (char*)d_ws;
    unsigned short* WqP = (unsigned short*)ws;               // 128 KB
    float* hqb    = (float*)(ws + 131072);                   // 32 KB
    float* s      = (float*)(ws + 163840);                   // 4 MB
    float* pml    = (float*)(ws + 4358144);                  // 32 KB
    float* sc     = (float*)(ws + 4390912);                  // 4 KB
    float* p_part = (float*)(ws + 4395008);                  // 4 MB

    prep_kernel<<<64, 256, 0, stream>>>(query, Wq, bq, WqP, hqb);
    fused_kernel<<<512, 512, 0, stream>>>(key, value, WqP, hqb, avec, s, p_part, pml);
    final_kernel<<<B_SZ * NUM_HEADS, 256, 0, stream>>>(p_part, pml, Wv, bv, out, sc);
    epass_kernel<<<B_SZ * 32, 256, 0, stream>>>(s, sc, out + B_SZ * HD);
}

// Round 21
// 133.283 us; speedup vs baseline: 1.7638x; 1.7638x over previous
//
#include <hip/hip_runtime.h>
#include <hip/hip_bf16.h>

#define NUM_HEADS 4
#define HD 256
#define QD 256
#define VD 256
#define B_SZ 32
#define N_NODES 8192
#define NEG_SLOPE 0.2f
#define CH 32            // rows per chunk
#define NCH 32           // chunks per strip (1024 rows)
#define KSTRIDE 1040     // key LDS row stride bytes

typedef short bf16x8 __attribute__((ext_vector_type(8)));
typedef float f32x4 __attribute__((ext_vector_type(4)));

static __device__ __forceinline__ unsigned short f2bf(float f) {
    __hip_bfloat16 h = __float2bfloat16(f);
    return *reinterpret_cast<unsigned short*>(&h);
}

static __device__ __forceinline__ void gload_lds16(const float* g, void* l) {
    __builtin_amdgcn_global_load_lds(
        (const __attribute__((address_space(1))) void*)g,
        (__attribute__((address_space(3))) void*)l, 16, 0, 0);
}

// ---------------------------------------------------------------------------
// Kernel 1: prep  (hqb + swizzled WqP pack; unchanged)
// ---------------------------------------------------------------------------
__global__ __launch_bounds__(256)
void prep_kernel(const float* __restrict__ query,
                 const float* __restrict__ Wq,
                 const float* __restrict__ bq,
                 unsigned short* __restrict__ WqP,
                 float* __restrict__ hqb) {
    int blk = blockIdx.x;
    int tid = threadIdx.x;
    if (blk < 32) {
        int b = blk, col = tid;
        float acc = 2.0f * bq[col];
#pragma unroll 16
        for (int k = 0; k < QD; ++k)
            acc += query[b * QD + k] * Wq[k * HD + col];
        hqb[b * HD + col] = acc;
    } else {
        int idx = blk - 32;
        int kstep = idx >> 2, g = idx & 3;
        int col = tid;
        int h = col >> 6, ct = (col >> 4) & 3, col16 = col & 15;
        unsigned short v[8];
#pragma unroll
        for (int j = 0; j < 8; ++j)
            v[j] = f2bf(Wq[(kstep * 32 + g * 8 + j) * HD + col]);
        *reinterpret_cast<uint4*>(
            WqP + kstep * 8192 + h * 2048 + ct * 512 + (g * 16 + col16) * 8) =
            *reinterpret_cast<uint4*>(v);
    }
}

// ---------------------------------------------------------------------------
// Kernel 2 (FUSED = R19 + SPLIT WAITS):
//  per chunk: barrier1 -> issue K(t+1),V(t+1) -> vmcnt(KEY only) -> barrier2
//  -> A-frags + MFMA + epilogue (value still landing) -> vmcnt(VALUE) ->
//  barrier3 -> PV. Value loads gain the whole MFMA/epilogue phase of
//  landing time; key wait no longer gated on value.
//  vmcnt accounting (issue order per wave: K(t)(4),V(t)(4),S(t-1)(1),
//  K(t+1)(4),V(t+1)(4)):
//    key-wait:  t==0 -> 12 ; 0<t<NCH-1 -> 13 ; t==NCH-1 -> 5
//    val-wait:  t==0 -> 8  ; 0<t<NCH-1 -> 9  ; t==NCH-1 -> 1
// ---------------------------------------------------------------------------
__global__ __launch_bounds__(512, 2)
void fused_kernel(const float* __restrict__ key,
                  const float* __restrict__ value,
                  const unsigned short* __restrict__ WqP,
                  const float* __restrict__ hqb,
                  const float* __restrict__ avec,
                  float* __restrict__ s,
                  float* __restrict__ p_part,
                  float* __restrict__ pml) {
    __shared__ __align__(16) char smem[2 * (CH * KSTRIDE) + 2 * (CH * 1024)];  // 132096 B

    char* kb0 = smem;
    char* kb1 = smem + CH * KSTRIDE;
    char* vb0 = smem + 2 * CH * KSTRIDE;
    char* vb1 = vb0 + CH * 1024;

    int bid = blockIdx.x;
    int b = bid >> 3, strip = bid & 7;
    int tid = threadIdx.x;
    int w = tid >> 6, lane = tid & 63;
    int col16 = lane & 15, g = (lane >> 4) & 3;
    int h = w & 3, half = w >> 2;
    int rowbase0 = strip * 1024;

    bf16x8 bfr[8][4];
    {
        const unsigned short* wp0 = WqP + h * 2048 + (g * 16 + col16) * 8;
#pragma unroll
        for (int ks = 0; ks < 8; ++ks)
#pragma unroll
            for (int ct = 0; ct < 4; ++ct)
                bfr[ks][ct] = *reinterpret_cast<const bf16x8*>(wp0 + ks * 8192 + ct * 512);
    }
    float av16[4][4], hq16[4][4];
#pragma unroll
    for (int ct = 0; ct < 4; ++ct)
#pragma unroll
        for (int r = 0; r < 4; ++r) {
            int d = ct * 16 + g * 4 + r;
            av16[ct][r] = avec[d];
            hq16[ct][r] = hqb[b * HD + h * 64 + d];
        }

    // force pre-loop loads resolved here (outside the loop)
    {
        int dummy = 0;
        float fd = 0.f;
#pragma unroll
        for (int ks = 0; ks < 8; ++ks)
#pragma unroll
            for (int ct = 0; ct < 4; ++ct)
                dummy ^= (int)bfr[ks][ct][0];
#pragma unroll
        for (int ct = 0; ct < 4; ++ct)
#pragma unroll
            for (int r = 0; r < 4; ++r)
                fd += av16[ct][r] + hq16[ct][r];
        asm volatile("" :: "v"(dummy), "v"(fd));
    }

    float mr = -1e30f, lr = 0.f;
    f32x4 pa = (f32x4){0.f, 0.f, 0.f, 0.f};

    // prologue: stage chunk 0 (K first, then V — order matters for vmcnt)
    {
        int rb = rowbase0;
#pragma unroll
        for (int r = 0; r < 4; ++r) {
            int lr_ = w * 4 + r;
            gload_lds16(key + ((size_t)(b * N_NODES + rb + lr_)) * QD + lane * 4,
                        kb0 + lr_ * KSTRIDE);
        }
#pragma unroll
        for (int r = 0; r < 4; ++r) {
            int lr_ = w * 4 + r;
            gload_lds16(value + ((size_t)(b * N_NODES + rb + lr_)) * VD + lane * 4,
                        vb0 + lr_ * 1024);
        }
    }

    for (int t = 0; t < NCH; ++t) {
        __builtin_amdgcn_s_barrier();          // everyone done computing t-1
        if (t + 1 < NCH) {
            char* kbn = ((t + 1) & 1) ? kb1 : kb0;
            char* vbn = ((t + 1) & 1) ? vb1 : vb0;
            int rb = rowbase0 + (t + 1) * CH;
#pragma unroll
            for (int r = 0; r < 4; ++r) {
                int lr_ = w * 4 + r;
                gload_lds16(key + ((size_t)(b * N_NODES + rb + lr_)) * QD + lane * 4,
                            kbn + lr_ * KSTRIDE);
            }
#pragma unroll
            for (int r = 0; r < 4; ++r) {
                int lr_ = w * 4 + r;
                gload_lds16(value + ((size_t)(b * N_NODES + rb + lr_)) * VD + lane * 4,
                            vbn + lr_ * 1024);
            }
            // KEY-wait only: V(t)(4) [+S(t-1)(1)] + K(t+1)(4) + V(t+1)(4) younger
            if (t == 0) asm volatile("s_waitcnt vmcnt(12)" ::: "memory");
            else        asm volatile("s_waitcnt vmcnt(13)" ::: "memory");
        } else {
            asm volatile("s_waitcnt vmcnt(5)" ::: "memory");   // key of last chunk
        }
        __builtin_amdgcn_s_barrier();          // everyone's KEY(t) visible
        __builtin_amdgcn_sched_barrier(0);

        const char* kb = (t & 1) ? kb1 : kb0;
        const char* vb = (t & 1) ? vb1 : vb0;
        int n0c = rowbase0 + t * CH;

        // ---- A-side fragments from key LDS (f32 -> bf16); lane&15 = key row
        bf16x8 a[8];
        {
            int krow = half * 16 + col16;
#pragma unroll
            for (int ks = 0; ks < 8; ++ks) {
                f32x4 lo = *reinterpret_cast<const f32x4*>(kb + krow * KSTRIDE + ks * 128 + g * 32);
                f32x4 hi = *reinterpret_cast<const f32x4*>(kb + krow * KSTRIDE + ks * 128 + g * 32 + 16);
                unsigned int u0, u1, u2, u3;
                asm("v_cvt_pk_bf16_f32 %0, %1, %2" : "=v"(u0) : "v"(lo[0]), "v"(lo[1]));
                asm("v_cvt_pk_bf16_f32 %0, %1, %2" : "=v"(u1) : "v"(lo[2]), "v"(lo[3]));
                asm("v_cvt_pk_bf16_f32 %0, %1, %2" : "=v"(u2) : "v"(hi[0]), "v"(hi[1]));
                asm("v_cvt_pk_bf16_f32 %0, %1, %2" : "=v"(u3) : "v"(hi[2]), "v"(hi[3]));
                uint4 tt = {u0, u1, u2, u3};
                a[ks] = *reinterpret_cast<bf16x8*>(&tt);
            }
        }

        // ---- MFMA swapped: C[d][keyrow] (value loads still landing under this)
        f32x4 acc[4];
#pragma unroll
        for (int ct = 0; ct < 4; ++ct) acc[ct] = (f32x4){0.f, 0.f, 0.f, 0.f};
#pragma unroll
        for (int ks = 0; ks < 8; ++ks)
#pragma unroll
            for (int ct = 0; ct < 4; ++ct)
                acc[ct] = __builtin_amdgcn_mfma_f32_16x16x32_bf16(bfr[ks][ct], a[ks], acc[ct], 0, 0, 0);

        // ---- epilogue: leaky + a-dot over d (regs) + 2 shfl over d-groups
        float dot = 0.f;
#pragma unroll
        for (int ct = 0; ct < 4; ++ct) {
#pragma unroll
            for (int r = 0; r < 4; ++r) {
                float pre = acc[ct][r] + hq16[ct][r];
                float tv = fmaxf(pre, NEG_SLOPE * pre);
                dot += av16[ct][r] * tv;
            }
        }
        dot += __shfl_xor(dot, 16, 64);
        dot += __shfl_xor(dot, 32, 64);

        if (lane < 16) {
            s[((size_t)(b * NUM_HEADS + h)) * N_NODES + n0c + half * 16 + lane] = dot;
        }

        // ---- online softmax over my 16 rows (reduce over col16 group)
        float mc = dot;
        mc = fmaxf(mc, __shfl_xor(mc, 1, 64));
        mc = fmaxf(mc, __shfl_xor(mc, 2, 64));
        mc = fmaxf(mc, __shfl_xor(mc, 4, 64));
        mc = fmaxf(mc, __shfl_xor(mc, 8, 64));
        float mnew = fmaxf(mr, mc);
        float ep = __expf(dot - mnew);
        float lc = ep;
        lc += __shfl_xor(lc, 1, 64);
        lc += __shfl_xor(lc, 2, 64);
        lc += __shfl_xor(lc, 4, 64);
        lc += __shfl_xor(lc, 8, 64);
        float scf = __expf(mr - mnew);
        pa *= scf;
        lr = lr * scf + lc;
        mr = mnew;

        // ---- VALUE-wait + barrier3, then PV (value gained the whole
        //      MFMA/epilogue phase of landing time)
        if (t == 0)            asm volatile("s_waitcnt vmcnt(8)" ::: "memory");
        else if (t < NCH - 1)  asm volatile("s_waitcnt vmcnt(9)" ::: "memory");
        else                   asm volatile("s_waitcnt vmcnt(1)" ::: "memory");
        __builtin_amdgcn_s_barrier();          // everyone's VALUE(t) visible
#pragma unroll
        for (int n = 0; n < 16; ++n) {
            f32x4 v = *reinterpret_cast<const f32x4*>(vb + (half * 16 + n) * 1024 + lane * 16);
            float e = __shfl(ep, n, 64);
            pa += e * v;
        }
    }

    int slot = bid * 8 + w;
    *reinterpret_cast<f32x4*>(p_part + (size_t)slot * 256 + lane * 4) = pa;
    if (lane == 0) {
        pml[slot * 2] = mr;
        pml[slot * 2 + 1] = lr;
    }
}

// ---------------------------------------------------------------------------
// Kernel 3: final. Per (b,h): 16 slots (8 strips x 2 halves); global M,L;
// rescale-reduce; @Wv + bias + relu; emit (M, invL).
// ---------------------------------------------------------------------------
__global__ __launch_bounds__(256)
void final_kernel(const float* __restrict__ p_part,
                  const float* __restrict__ pml,
                  const float* __restrict__ Wv,
                  const float* __restrict__ bv,
                  float* __restrict__ hout,
                  float* __restrict__ sc) {
    int bh = blockIdx.x;
    int b = bh >> 2, h = bh & 3;
    int tid = threadIdx.x;

    int slots[16];
    float mv[16], lv[16];
    float M = -1e30f;
#pragma unroll
    for (int i = 0; i < 16; ++i) {
        int strip = i >> 1, hf = i & 1;
        slots[i] = (b * 8 + strip) * 8 + hf * 4 + h;
        mv[i] = pml[slots[i] * 2];
        lv[i] = pml[slots[i] * 2 + 1];
        M = fmaxf(M, mv[i]);
    }
    float L = 0.f, acc = 0.f;
#pragma unroll
    for (int i = 0; i < 16; ++i) {
        float wf = __expf(mv[i] - M);
        L += wf * lv[i];
        acc += wf * p_part[(size_t)slots[i] * 256 + tid];
    }
    float invL = 1.0f / L;
    if (tid == 0) {
        sc[bh * 2] = M;
        sc[bh * 2 + 1] = invL;
    }
    __shared__ float ps[256];
    ps[tid] = acc * invL;
    __syncthreads();

    int d = tid & 63, kr = tid >> 6;
    float a2 = 0.f;
#pragma unroll 8
    for (int k = kr * 64; k < kr * 64 + 64; ++k)
        a2 += ps[k] * Wv[k * HD + h * 64 + d];
    __shared__ float rs[4][64];
    rs[kr][d] = a2;
    __syncthreads();
    if (tid < 64) {
        float o = bv[h * 64 + tid] + rs[0][tid] + rs[1][tid] + rs[2][tid] + rs[3][tid];
        hout[b * HD + h * 64 + tid] = fmaxf(o, 0.f);
    }
}

// ---------------------------------------------------------------------------
// Kernel 4: e-pass. e_out[b,n,h] = exp(s[b,h,n]-M)*invL.
// ---------------------------------------------------------------------------
__global__ __launch_bounds__(256)
void epass_kernel(const float* __restrict__ s,
                  const float* __restrict__ sc,
                  float* __restrict__ e_out) {
    int bid = blockIdx.x;
    int b = bid >> 5, t = bid & 31;
    int n = t * 256 + threadIdx.x;
    float4 ev;
#pragma unroll
    for (int h = 0; h < 4; ++h) {
        float M = sc[(b * 4 + h) * 2];
        float invL = sc[(b * 4 + h) * 2 + 1];
        float sv = s[((size_t)(b * 4 + h)) * N_NODES + n];
        (&ev.x)[h] = __expf(sv - M) * invL;
    }
    *reinterpret_cast<float4*>(e_out + ((size_t)(b * N_NODES + n)) * 4) = ev;
}

extern "C" void kernel_launch(void* const* d_in, const int* in_sizes, int n_in,
                              void* d_out, int out_size, void* d_ws, size_t ws_size,
                              hipStream_t stream) {
    const float* query = (const float*)d_in[0];
    const float* key   = (const float*)d_in[1];
    const float* value = (const float*)d_in[2];
    const float* Wq    = (const float*)d_in[3];
    const float* bq    = (const float*)d_in[4];
    const float* Wv    = (const float*)d_in[5];
    const float* bv    = (const float*)d_in[6];
    const float* avec  = (const float*)d_in[7];
    float* out = (float*)d_out;

    char* ws = (char*)d_ws;
    unsigned short* WqP = (unsigned short*)ws;               // 128 KB
    float* hqb    = (float*)(ws + 131072);                   // 32 KB
    float* s      = (float*)(ws + 163840);                   // 4 MB
    float* pml    = (float*)(ws + 4358144);                  // 16 KB
    float* sc     = (float*)(ws + 4374528);                  // 4 KB
    float* p_part = (float*)(ws + 4378624);                  // 2 MB

    prep_kernel<<<64, 256, 0, stream>>>(query, Wq, bq, WqP, hqb);
    fused_kernel<<<256, 512, 0, stream>>>(key, value, WqP, hqb, avec, s, p_part, pml);
    final_kernel<<<B_SZ * NUM_HEADS, 256, 0, stream>>>(p_part, pml, Wv, bv, out, sc);
    epass_kernel<<<B_SZ * 32, 256, 0, stream>>>(s, sc, out + B_SZ * HD);
}